// Round 3
// baseline (130.230 us; speedup 1.0000x reference)
//
#include <hip/hip_runtime.h>

// TinyQuantumClassifier, collapsed + fused.
//
// z0 = (1, cos x1, sin x1) . W . (1, cos x2, sin x2)^T  with uniform 3x3 W
// derived from theta (see derivation in round-1 journal). Single kernel:
// thread 0 of each block computes W into LDS (~0.5 us serial chain) while
// every thread's feature load is already in flight; barrier; then 4 native
// trig + ~16 FMA + coalesced float2 store per thread (2 samples/thread).
// Memory-bound: 96 MiB mandatory traffic -> ~16 us kernel floor.

__device__ void compute_W(const float* __restrict__ theta, float* __restrict__ W) {
    float ang[4] = {theta[0], theta[1], theta[2], theta[3]};

    float M[4][4], K[4][4], T2[4][4];
    for (int i = 0; i < 4; ++i)
        for (int j = 0; j < 4; ++j) M[i][j] = (i == j) ? 1.f : 0.f;

    for (int l = 0; l < 2; ++l) {
        float ca = cosf(0.5f * ang[2 * l]),     sa = sinf(0.5f * ang[2 * l]);
        float cb = cosf(0.5f * ang[2 * l + 1]), sb = sinf(0.5f * ang[2 * l + 1]);
        float A[2][2]  = {{ca, -sa}, {sa, ca}};   // wire0 rotation
        float Bb[2][2] = {{cb, -sb}, {sb, cb}};   // wire1 rotation
        // K = A kron B, flat index (i,j) -> 2i+j (i = wire0)
        for (int i = 0; i < 2; ++i)
            for (int j = 0; j < 2; ++j)
                for (int k = 0; k < 2; ++k)
                    for (int m = 0; m < 2; ++m)
                        K[2 * i + j][2 * k + m] = A[i][k] * Bb[j][m];
        // T2 = K * M
        for (int i = 0; i < 4; ++i)
            for (int j = 0; j < 4; ++j) {
                float acc = 0.f;
                for (int k = 0; k < 4; ++k) acc += K[i][k] * M[k][j];
                T2[i][j] = acc;
            }
        // CNOT(0,1): swap flat rows 2,3 ((1,0) <-> (1,1))
        for (int j = 0; j < 4; ++j) {
            M[0][j] = T2[0][j];
            M[1][j] = T2[1][j];
            M[2][j] = T2[3][j];
            M[3][j] = T2[2][j];
        }
    }

    // Q = M^T D M, D = diag(1,1,-1,-1)
    float Q[4][4];
    for (int r = 0; r < 4; ++r)
        for (int c = 0; c < 4; ++c) {
            float acc = 0.f;
            for (int t = 0; t < 4; ++t) {
                float d = (t < 2) ? 1.f : -1.f;
                acc += M[t][r] * d * M[t][c];
            }
            Q[r][c] = acc;
        }

    // Reduce half-angle products p_a p_c to basis {1, cos x, sin x}
    const float T[2][2][3] = {{{0.5f, 0.5f, 0.f}, {0.f, 0.f, 0.5f}},
                              {{0.f, 0.f, 0.5f}, {0.5f, -0.5f, 0.f}}};
    for (int m = 0; m < 3; ++m)
        for (int n = 0; n < 3; ++n) {
            float acc = 0.f;
            for (int a = 0; a < 2; ++a)
                for (int b = 0; b < 2; ++b)
                    for (int c = 0; c < 2; ++c)
                        for (int d = 0; d < 2; ++d)
                            acc += Q[2 * a + b][2 * c + d] * T[a][c][m] * T[b][d][n];
            W[3 * m + n] = acc;
        }
}

__global__ __launch_bounds__(256) void tqc_fused(
    const float4* __restrict__ feat4,  // feat4[t] = (x1,x2) for 2 samples
    const float*  __restrict__ theta,  // 4 uniform floats
    float2*       __restrict__ out2,   // 2 results per thread
    int n2)
{
    __shared__ float Ws[9];

    int t = blockIdx.x * blockDim.x + threadIdx.x;
    bool valid = t < n2;

    // Issue the streaming load BEFORE the setup barrier so VMEM is in
    // flight while thread 0 runs the serial W chain.
    float4 f = make_float4(0.f, 0.f, 0.f, 0.f);
    if (valid) f = feat4[t];

    if (threadIdx.x == 0) compute_W(theta, Ws);
    __syncthreads();

    // Same-address LDS reads -> broadcast, conflict-free.
    float w0 = Ws[0], w1 = Ws[1], w2 = Ws[2];
    float w3 = Ws[3], w4 = Ws[4], w5 = Ws[5];
    float w6 = Ws[6], w7 = Ws[7], w8 = Ws[8];

    if (!valid) return;

    float s1, c1, s2, c2;
    __sincosf(f.x, &s1, &c1);
    __sincosf(f.y, &s2, &c2);
    float r0 = (w0 + w1 * c2 + w2 * s2)
             + c1 * (w3 + w4 * c2 + w5 * s2)
             + s1 * (w6 + w7 * c2 + w8 * s2);

    __sincosf(f.z, &s1, &c1);
    __sincosf(f.w, &s2, &c2);
    float r1 = (w0 + w1 * c2 + w2 * s2)
             + c1 * (w3 + w4 * c2 + w5 * s2)
             + s1 * (w6 + w7 * c2 + w8 * s2);

    out2[t] = make_float2(r0, r1);
}

extern "C" void kernel_launch(void* const* d_in, const int* in_sizes, int n_in,
                              void* d_out, int out_size, void* d_ws, size_t ws_size,
                              hipStream_t stream) {
    const float* feat  = (const float*)d_in[0];  // [B,2] f32
    const float* theta = (const float*)d_in[1];  // [2,2] f32
    float* out = (float*)d_out;                  // [B,1] f32

    int b  = in_sizes[0] / 2;  // samples
    int n2 = b / 2;            // threads, 2 samples each (B even)

    int block = 256;
    int grid = (n2 + block - 1) / block;
    tqc_fused<<<grid, block, 0, stream>>>(
        (const float4*)feat, theta, (float2*)out, n2);
}

// Round 4
// 96.270 us; speedup vs baseline: 1.3528x; 1.3528x over previous
//
#include <hip/hip_runtime.h>

// TinyQuantumClassifier — closed form (Heisenberg-picture pullback of Z0):
//   z0 = cos(A)*cos(x1+B) - sin(A)*sin(x1+B)*sin(x2+C)
// where B = theta[0,0], C = theta[0,1], A = theta[1,0]; theta[1,1] drops out
// (last CNOT and last wire-1 RY commute with Z0). Verified: theta=0 -> cos x1.
//
// 4 samples/thread: two grid-strided float4 loads (each instruction fully
// coalesced), 3 fast-trig + 3 FMA per sample, two coalesced float2 stores.
// No setup kernel, no LDS, no barrier. Memory-bound: ~12 B/sample.

__global__ __launch_bounds__(256) void tqc_closed(
    const float4* __restrict__ feat4,  // feat4[i] = (x1,x2) for 2 samples
    const float*  __restrict__ theta,  // 4 uniform floats (flat [2,2])
    float2*       __restrict__ out2,   // 2 results per float2
    int half)                          // = (#float4)/2; thread t handles i=t and i=t+half
{
    int t = blockIdx.x * blockDim.x + threadIdx.x;
    if (t >= half) return;

    float Bc = theta[0];               // layer0 wire0 (uniform -> scalar loads)
    float Cc = theta[1];               // layer0 wire1
    float sA, cA;
    __sincosf(theta[2], &sA, &cA);     // layer1 wire0

    // Issue both streaming loads up front.
    float4 f0 = feat4[t];
    float4 f1 = feat4[t + half];

    float s1, c1, s2;

    __sincosf(f0.x + Bc, &s1, &c1);
    s2 = __sinf(f0.y + Cc);
    float r0 = cA * c1 - sA * s1 * s2;

    __sincosf(f0.z + Bc, &s1, &c1);
    s2 = __sinf(f0.w + Cc);
    float r1 = cA * c1 - sA * s1 * s2;

    out2[t] = make_float2(r0, r1);

    __sincosf(f1.x + Bc, &s1, &c1);
    s2 = __sinf(f1.y + Cc);
    r0 = cA * c1 - sA * s1 * s2;

    __sincosf(f1.z + Bc, &s1, &c1);
    s2 = __sinf(f1.w + Cc);
    r1 = cA * c1 - sA * s1 * s2;

    out2[t + half] = make_float2(r0, r1);
}

extern "C" void kernel_launch(void* const* d_in, const int* in_sizes, int n_in,
                              void* d_out, int out_size, void* d_ws, size_t ws_size,
                              hipStream_t stream) {
    const float* feat  = (const float*)d_in[0];  // [B,2] f32
    const float* theta = (const float*)d_in[1];  // [2,2] f32
    float* out = (float*)d_out;                  // [B,1] f32

    int b    = in_sizes[0] / 2;  // samples (8388608)
    int n4   = b / 2;            // float4 count (2 samples each)
    int half = n4 / 2;           // threads (4 samples each)

    int block = 256;
    int grid = (half + block - 1) / block;
    tqc_closed<<<grid, block, 0, stream>>>(
        (const float4*)feat, theta, (float2*)out, half);
}